// Round 12
// baseline (2138.975 us; speedup 1.0000x reference)
//
#include <hip/hip_runtime.h>
#include <hip/hip_bf16.h>
#include <stdint.h>

// ---------------- types / helpers ----------------
typedef unsigned short u16;
typedef __attribute__((ext_vector_type(8))) short short8;   // 8 bf16 (4 VGPRs)
typedef __attribute__((ext_vector_type(4))) float f32x4;

__device__ __forceinline__ u16 f2bf(float f) {  // RNE float->bf16
  union { float f; unsigned u; } v; v.f = f;
  unsigned r = v.u + 0x7fffu + ((v.u >> 16) & 1u);
  return (u16)(r >> 16);
}

__device__ __forceinline__ void g2lds16(const u16* g, u16* l) {
  // async global->LDS, 16B/lane; LDS dest = wave-uniform base + lane*16
  __builtin_amdgcn_global_load_lds(
      (const __attribute__((address_space(1))) uint32_t*)g,
      (__attribute__((address_space(3))) uint32_t*)l, 16, 0, 0);
}

#define BAR()   asm volatile("s_barrier" ::: "memory")
#define LGKM0() asm volatile("s_waitcnt lgkmcnt(0)" ::: "memory")
#define VM8()   asm volatile("s_waitcnt vmcnt(8)" ::: "memory")
#define VM4()   asm volatile("s_waitcnt vmcnt(4)" ::: "memory")
#define VM0()   asm volatile("s_waitcnt vmcnt(0)" ::: "memory")
#define PRIO1() __builtin_amdgcn_s_setprio(1)
#define PRIO0() __builtin_amdgcn_s_setprio(0)

// Q pre-scale: 1/sqrt(64) * log2(e), folded into Q so attn uses exp2 directly
#define QSCALE 0.18033688f

// -------- merged prep: hs convert + ehs convert_pad + vt zero + 4x weight fusion --------
__global__ __launch_bounds__(256) void k_prepc(
    const float* __restrict__ hs, u16* __restrict__ hs_b,
    const float* __restrict__ ehs, u16* __restrict__ ehs_b,
    u16* __restrict__ vt,
    const float* __restrict__ Wq, const float* __restrict__ qd, const float* __restrict__ qu, u16* __restrict__ wq_t,
    const float* __restrict__ Wk, const float* __restrict__ kd, const float* __restrict__ ku, u16* __restrict__ wk_t,
    const float* __restrict__ Wv, const float* __restrict__ vd, const float* __restrict__ vu, u16* __restrict__ wv_t,
    const float* __restrict__ Wo, const float* __restrict__ od, const float* __restrict__ ou, u16* __restrict__ wo_t) {
  __shared__ float dn[64][65];
  __shared__ float up[64][17];
  int bid = blockIdx.x;

  if (bid < 40960) {   // hs f32 -> bf16
    int i = bid * 256 + threadIdx.x;
    const float4* p = (const float4*)(hs + (size_t)i * 8);
    float4 a = p[0], b = p[1];
    short8 o;
    o[0] = (short)f2bf(a.x); o[1] = (short)f2bf(a.y);
    o[2] = (short)f2bf(a.z); o[3] = (short)f2bf(a.w);
    o[4] = (short)f2bf(b.x); o[5] = (short)f2bf(b.y);
    o[6] = (short)f2bf(b.z); o[7] = (short)f2bf(b.w);
    *(short8*)(hs_b + (size_t)i * 8) = o;
    return;
  }
  bid -= 40960;
  if (bid < 480) {   // convert_pad: ehs
    int i = bid * 256 + threadIdx.x;
    short8 o;
    if (i < 118272) {
      const float4* p = (const float4*)(ehs + (size_t)i * 8);
      float4 a = p[0], b = p[1];
      o[0] = (short)f2bf(a.x); o[1] = (short)f2bf(a.y);
      o[2] = (short)f2bf(a.z); o[3] = (short)f2bf(a.w);
      o[4] = (short)f2bf(b.x); o[5] = (short)f2bf(b.y);
      o[6] = (short)f2bf(b.z); o[7] = (short)f2bf(b.w);
    } else {
#pragma unroll
      for (int e = 0; e < 8; ++e) o[e] = 0;
    }
    *(short8*)(ehs_b + (size_t)i * 8) = o;
    return;
  }
  bid -= 480;
  if (bid < 960) {   // zero vt (16*20*64*96 u16)
    int i = bid * 256 + threadIdx.x;
    short8 z;
#pragma unroll
    for (int e = 0; e < 8; ++e) z[e] = 0;
    *(short8*)(vt + (size_t)i * 8) = z;
    return;
  }
  bid -= 960;
  const float *W, *dng, *upg; u16* Wt; int K, bx, by;
  if (bid < 1600)      { W = Wq; dng = qd; upg = qu; Wt = wq_t; K = 1280; bx = bid % 20; by = bid / 20; }
  else if (bid < 2560) { bid -= 1600; W = Wk; dng = kd; upg = ku; Wt = wk_t; K = 768;  bx = bid % 12; by = bid / 12; }
  else if (bid < 3520) { bid -= 2560; W = Wv; dng = vd; upg = vu; Wt = wv_t; K = 768;  bx = bid % 12; by = bid / 12; }
  else                 { bid -= 3520; W = Wo; dng = od; upg = ou; Wt = wo_t; K = 1280; bx = bid % 20; by = bid / 20; }
  const int N = 1280;
  const int k0 = bx * 64, n0 = by * 16;
  const int kc = threadIdx.x & 63, ty = threadIdx.x >> 6;
  for (int c = threadIdx.x; c < 4096; c += 256)
    dn[c >> 6][c & 63] = dng[(size_t)(k0 + (c >> 6)) * 64 + (c & 63)];
  for (int c = threadIdx.x; c < 1024; c += 256)
    up[c >> 4][c & 15] = upg[(size_t)(c >> 4) * N + n0 + (c & 15)];
  __syncthreads();
  float acc[4];
#pragma unroll
  for (int e = 0; e < 4; ++e)
    acc[e] = W[(size_t)(k0 + kc) * N + n0 + ty * 4 + e];
#pragma unroll 16
  for (int r = 0; r < 64; ++r) {
    float d = dn[kc][r];
#pragma unroll
    for (int e = 0; e < 4; ++e) acc[e] += d * up[r][ty * 4 + e];
  }
#pragma unroll
  for (int e = 0; e < 4; ++e)
    Wt[(size_t)(n0 + ty * 4 + e) * K + k0 + kc] = f2bf(acc[e]);
}

// ---------------- K/V projections (z=0: K row-major; z=1: V transposed to vt) ----------------
__global__ __launch_bounds__(256) void k_gemmKV(const u16* __restrict__ A,
                                                const u16* __restrict__ BtK,
                                                const u16* __restrict__ BtV,
                                                u16* __restrict__ CK,
                                                u16* __restrict__ VT) {
  constexpr int N = 1280, K = 768;
  const u16* Bt = blockIdx.z ? BtV : BtK;
  __shared__ __align__(16) u16 As[128 * 32];
  __shared__ __align__(16) u16 Bs[128 * 32];
  const int tid = threadIdx.x, lane = tid & 63, w = tid >> 6;
  const int n0 = blockIdx.x * 128, m0 = blockIdx.y * 128;
  const int wm = (w >> 1) * 64, wn = (w & 1) * 64;

  f32x4 acc[4][4];
  f32x4 zf = {0.f, 0.f, 0.f, 0.f};
#pragma unroll
  for (int i = 0; i < 4; ++i)
#pragma unroll
    for (int j = 0; j < 4; ++j) acc[i][j] = zf;

  const int c0 = w, c1 = w + 4;
  const int rA0 = c0 * 16 + (lane >> 2), rA1 = c1 * 16 + (lane >> 2);
  const int kp = (lane & 3) * 8;
  const u16* gA0 = A + (size_t)(m0 + rA0) * K + kp;
  const u16* gA1 = A + (size_t)(m0 + rA1) * K + kp;
  const u16* gB0 = Bt + (size_t)(n0 + rA0) * K + kp;
  const u16* gB1 = Bt + (size_t)(n0 + rA1) * K + kp;
  u16* lA0 = As + c0 * 512;  u16* lA1 = As + c1 * 512;
  u16* lB0 = Bs + c0 * 512;  u16* lB1 = Bs + c1 * 512;

  const int fr = lane & 15, kg = (lane >> 4) * 8;

  for (int k0 = 0; k0 < K; k0 += 32) {
    g2lds16(gA0 + k0, lA0);
    g2lds16(gA1 + k0, lA1);
    g2lds16(gB0 + k0, lB0);
    g2lds16(gB1 + k0, lB1);
    __syncthreads();
    short8 af[4], bf[4];
#pragma unroll
    for (int i = 0; i < 4; ++i)
      af[i] = *(const short8*)(As + (wm + i * 16 + fr) * 32 + kg);
#pragma unroll
    for (int j = 0; j < 4; ++j)
      bf[j] = *(const short8*)(Bs + (wn + j * 16 + fr) * 32 + kg);
#pragma unroll
    for (int i = 0; i < 4; ++i)
#pragma unroll
      for (int j = 0; j < 4; ++j)
        acc[i][j] = __builtin_amdgcn_mfma_f32_16x16x32_bf16(af[i], bf[j], acc[i][j], 0, 0, 0);
    __syncthreads();
  }

  const int rb = (lane >> 4) * 4;
  if (blockIdx.z == 0) {
#pragma unroll
    for (int i = 0; i < 4; ++i)
#pragma unroll
      for (int j = 0; j < 4; ++j) {
        int col = n0 + wn + j * 16 + fr;
#pragma unroll
        for (int r = 0; r < 4; ++r) {
          int row = m0 + wm + i * 16 + rb + r;
          CK[(size_t)row * N + col] = f2bf(acc[i][j][r]);
        }
      }
  } else {
#pragma unroll
    for (int i = 0; i < 4; ++i)
#pragma unroll
      for (int j = 0; j < 4; ++j) {
        int col = n0 + wn + j * 16 + fr;
        int h = col >> 6, d = col & 63;
#pragma unroll
        for (int r = 0; r < 4; ++r) {
          int row = m0 + wm + i * 16 + rb + r;
          if (row < 1232) {
            int b2 = row / 77;
            int s2 = row - b2 * 77;
            VT[(size_t)((b2 * 20 + h) * 64 + d) * 96 + s2] = f2bf(acc[i][j][r]);
          }
        }
      }
  }
}

// ================= shared pieces for the 256x256 BK=64 kernel (qa) =================
#define GEMM256_COMMON()                                                       \
  constexpr int K = 1280;                                                      \
  constexpr int N = 1280;                                                      \
  __shared__ __align__(16) u16 lds[2][2][2][128 * 64];                         \
  const int lane = threadIdx.x & 63, w = threadIdx.x >> 6;                     \
  const int bid = blockIdx.x;                                                  \
  const int tile = (bid & 7) * 160 + (bid >> 3);                               \
  const int n0 = (tile % 5) * 256, m0 = (tile / 5) * 256;                      \
  const int l0 = w * 2;                                                        \
  const int fr = lane & 15;                                                    \
  const int q16b = (lane >> 4) * 16;                                           \
  const int xr = (fr & 7) << 4;                                                \
  const int cT0 = ((0 + q16b) ^ xr) >> 1;                                      \
  const int cT1 = ((64 + q16b) ^ xr) >> 1;                                     \
  const int ha = w >> 2;                                                       \
  const int hb = (w & 3) >> 1;                                                 \
  const int rB0 = (w & 1) * 64;

#define GSRC_INIT(A_, Bt_)                                                     \
  const u16* gsrc[4][2];                                                       \
  _Pragma("unroll") for (int s2 = 0; s2 < 4; ++s2) {                           \
    const int side = s2 >> 1, h = s2 & 1;                                      \
    _Pragma("unroll") for (int l = 0; l < 2; ++l) {                            \
      const int o = (l0 + l) * 1024 + lane * 16;                               \
      const int row = o >> 7;                                                  \
      const int scol = (o & 127) ^ ((row & 7) << 4);                           \
      const u16* base = side ? ((Bt_) + (size_t)(n0 + h * 128 + row) * K)      \
                             : ((A_) + (size_t)(m0 + h * 128 + row) * K);      \
      gsrc[s2][l] = base + (scol >> 1);                                        \
    }                                                                          \
  }

#define STAGE_HALF(P, SIDE, H, KT)                                             \
  do {                                                                         \
    g2lds16(gsrc[(SIDE) * 2 + (H)][0] + (KT) * 64,                             \
            &lds[P][SIDE][H][(l0 + 0) * 512]);                                 \
    g2lds16(gsrc[(SIDE) * 2 + (H)][1] + (KT) * 64,                             \
            &lds[P][SIDE][H][(l0 + 1) * 512]);                                 \
  } while (0)

#define STAGE_FULL(P, KT)                                                      \
  do {                                                                         \
    STAGE_HALF(P, 0, 0, KT); STAGE_HALF(P, 0, 1, KT);                          \
    STAGE_HALF(P, 1, 0, KT); STAGE_HALF(P, 1, 1, KT);                          \
  } while (0)

#define LOAD_AF(P, IB)                                                         \
  do {                                                                         \
    _Pragma("unroll") for (int ii = 0; ii < 4; ++ii) {                         \
      const u16* rp = &lds[P][0][ha][(((IB) + ii) * 16 + fr) * 64];            \
      af[ii][0] = *(const short8*)(rp + cT0);                                  \
      af[ii][1] = *(const short8*)(rp + cT1);                                  \
    }                                                                          \
  } while (0)

#define LOAD_BF(P, JB)                                                         \
  do {                                                                         \
    _Pragma("unroll") for (int jj = 0; jj < 2; ++jj) {                         \
      const u16* rp = &lds[P][1][hb][(rB0 + ((JB) + jj) * 16 + fr) * 64];      \
      bf[(JB) + jj][0] = *(const short8*)(rp + cT0);                           \
      bf[(JB) + jj][1] = *(const short8*)(rp + cT1);                           \
    }                                                                          \
  } while (0)

#define MFMA_Q(IO, JB)                                                         \
  do {                                                                         \
    _Pragma("unroll") for (int t = 0; t < 2; ++t)                              \
        _Pragma("unroll") for (int ii = 0; ii < 4; ++ii)                       \
            _Pragma("unroll") for (int jj = 0; jj < 2; ++jj)                   \
                acc[(IO) + ii][(JB) + jj] =                                    \
        __builtin_amdgcn_mfma_f32_16x16x32_bf16(                               \
            af[ii][t], bf[(JB) + jj][t], acc[(IO) + ii][(JB) + jj], 0, 0, 0);  \
  } while (0)

#define ACC_ZERO()                                                             \
  do {                                                                         \
    f32x4 zf = {0.f, 0.f, 0.f, 0.f};                                           \
    _Pragma("unroll") for (int i = 0; i < 8; ++i)                              \
        _Pragma("unroll") for (int j = 0; j < 4; ++j) acc[i][j] = zf;          \
  } while (0)

#define GEMM256_MAINLOOP()                                                     \
  do {                                                                         \
    STAGE_FULL(0, 0);                                                          \
    STAGE_FULL(1, 1);                                                          \
    VM8();                                                                     \
    BAR();                                                                     \
    for (int t = 0; t < 20; ++t) {                                             \
      const int P = t & 1;                                                     \
      LOAD_AF(P, 0);                                                           \
      LOAD_BF(P, 0);                                                           \
      LOAD_BF(P, 2);                                                           \
      MFMA_Q(0, 0);                                                            \
      MFMA_Q(0, 2);                                                            \
      LOAD_AF(P, 4);                                                           \
      MFMA_Q(4, 2);                                                            \
      LGKM0();                                                                 \
      BAR();                                                                   \
      if (t < 18) STAGE_FULL(P, t + 2);                                        \
      PRIO1(); MFMA_Q(4, 0); PRIO0();                                          \
      if (t < 18) { VM8(); } else { VM0(); }                                   \
      BAR();                                                                   \
    }                                                                          \
  } while (0)

// ---------------- O-GEMM (EXPERIMENT): BK=32, 64 KB LDS, 2 blocks/CU ----------------
// Swizzle for 64B rows (4 granules): chunk ^= (row>>1)&3 -> bank word =
// 16*(row&1) + 4*(kq^((row>>1)&3)): 16 lanes cover 8 groups, 2-way = free.
// Applied both-sides: pre-swizzled gload source + same-involution ds_read.
__global__ __launch_bounds__(512, 4) void k_gemm256h(const u16* __restrict__ A,
                                                     const u16* __restrict__ Bt,
                                                     float* __restrict__ Cout,
                                                     const float* __restrict__ bias) {
  constexpr int K = 1280;
  constexpr int N = 1280;
  __shared__ __align__(16) u16 lds[2][2][2][128 * 32];  // 64 KB
  const int tid = threadIdx.x, lane = tid & 63, w = tid >> 6;
  const int bid = blockIdx.x;
  const int tile = (bid & 7) * 160 + (bid >> 3);
  const int n0 = (tile % 5) * 256, m0 = (tile / 5) * 256;
  const int fr = lane & 15, kq = lane >> 4;
  const int ha = w >> 2, hb = (w & 3) >> 1, rB0 = (w & 1) * 64;
  const int cH = (kq ^ ((fr >> 1) & 3)) * 8;   // swizzled read chunk (u16 off)

  // staging: one g2lds16 per thread per (side,h); dest linear tid*16B
  const int srow = tid >> 2;
  const int schunk = (tid & 3) ^ ((srow >> 1) & 3);
  const u16* gsrc[4];
#pragma unroll
  for (int s2 = 0; s2 < 4; ++s2) {
    const int side = s2 >> 1, h = s2 & 1;
    const u16* base = side ? (Bt + (size_t)(n0 + h * 128 + srow) * K)
                           : (A + (size_t)(m0 + h * 128 + srow) * K);
    gsrc[s2] = base + schunk * 8;
  }

#define HSTAGE(P, KT)                                                          \
  do {                                                                         \
    _Pragma("unroll") for (int s2 = 0; s2 < 4; ++s2)                           \
      g2lds16(gsrc[s2] + (KT) * 32, &lds[P][s2 >> 1][s2 & 1][tid * 8]);        \
  } while (0)
#define HLOAD_AF(P, IB)                                                        \
  do {                                                                         \
    _Pragma("unroll") for (int ii = 0; ii < 4; ++ii)                           \
      af[ii] = *(const short8*)(&lds[P][0][ha][(((IB) + ii) * 16 + fr) * 32 + cH]); \
  } while (0)
#define HLOAD_BF(P, JB)                                                        \
  do {                                                                         \
    _Pragma("unroll") for (int jj = 0; jj < 2; ++jj)                           \
      bf[(JB) + jj] = *(const short8*)(&lds[P][1][hb][(rB0 + ((JB) + jj) * 16 + fr) * 32 + cH]); \
  } while (0)
#define HMFMA(IO, JB)                                                          \
  do {                                                                         \
    _Pragma("unroll") for (int ii = 0; ii < 4; ++ii)                           \
        _Pragma("unroll") for (int jj = 0; jj < 2; ++jj)                       \
            acc[(IO) + ii][(JB) + jj] =                                        \
        __builtin_amdgcn_mfma_f32_16x16x32_bf16(                               \
            af[ii], bf[(JB) + jj], acc[(IO) + ii][(JB) + jj], 0, 0, 0);        \
  } while (0)

  short8 af[4], bf[4];
  f32x4 acc[8][4];
  {
    f32x4 zf = {0.f, 0.f, 0.f, 0.f};
#pragma unroll
    for (int i = 0; i < 8; ++i)
#pragma unroll
      for (int j = 0; j < 4; ++j) acc[i][j] = zf;
  }

  // prologue: K-tiles 0 (buf0), 1 (buf1); drain tile0, keep tile1's 4 in flight
  HSTAGE(0, 0);
  HSTAGE(1, 1);
  VM4();
  BAR();

  for (int t = 0; t < 40; ++t) {
    const int P = t & 1;
    HLOAD_AF(P, 0);
    HLOAD_BF(P, 0);
    HLOAD_BF(P, 2);
    HMFMA(0, 0);
    HMFMA(0, 2);
    HLOAD_AF(P, 4);
    HMFMA(4, 2);
    LGKM0();
    BAR();
    if (t < 38) HSTAGE(P, t + 2);
    PRIO1(); HMFMA(4, 0); PRIO0();
    if (t < 38) { VM4(); }            // drain tile t+1's 4; t+2 stays in flight
    else if (t == 38) { VM0(); }      // drain tile 39 before its reads
    BAR();
  }
#undef HSTAGE
#undef HLOAD_AF
#undef HLOAD_BF
#undef HMFMA

  const int rb = kq * 4;
  const int orow = m0 + (w >> 2) * 128;
  const int ocol = n0 + (w & 3) * 64;
#pragma unroll
  for (int i = 0; i < 8; ++i)
#pragma unroll
    for (int j = 0; j < 4; ++j) {
      const int col = ocol + j * 16 + fr;
      const float bj = bias[col];
#pragma unroll
      for (int r = 0; r < 4; ++r)
        Cout[(size_t)(orow + i * 16 + rb + r) * N + col] = acc[i][j][r] + bj;
    }
}

// ---------------- Q-GEMM + FUSED ATTENTION (unchanged from R11) ----------------
__global__ __launch_bounds__(512, 1) void k_gemm256qa(const u16* __restrict__ A,
                                                      const u16* __restrict__ Bt,
                                                      const u16* __restrict__ Kbuf,
                                                      const u16* __restrict__ VTg,
                                                      u16* __restrict__ Obuf) {
  GEMM256_COMMON();
  GSRC_INIT(A, Bt);
  short8 af[4][2], bf[4][2];
  f32x4 acc[8][4];
  ACC_ZERO();
  GEMM256_MAINLOOP();

  const int bb = (tile / 5) >> 4;             // batch
  const int hd = (tile % 5) * 4 + (w & 3);    // head
  const int orow = m0 + (w >> 2) * 128;
  const int cb = fr, kq = lane >> 4, kgu = kq * 8;

  u16* ldsb = (u16*)lds;
  u16* Qc = ldsb + w * 2304;                  // [32][72]
  u16* Pw = ldsb + 8 * 2304 + w * 3328;       // [32][104]

  {
    short8 zz;
#pragma unroll
    for (int e = 0; e < 8; ++e) zz[e] = 0;
    *(short8*)(Pw + (lane >> 1) * 104 + 80 + (lane & 1) * 8) = zz;
  }

  short8 kf[5][2];
#pragma unroll
  for (int j = 0; j < 5; ++j)
#pragma unroll
    for (int t2 = 0; t2 < 2; ++t2)
      kf[j][t2] = *(const short8*)(Kbuf + (size_t)(bb * 77 + j * 16 + cb) * 1280 +
                                   hd * 64 + t2 * 32 + kgu);
  short8 vf[4][3];
#pragma unroll
  for (int n = 0; n < 4; ++n)
#pragma unroll
    for (int t2 = 0; t2 < 3; ++t2)
      vf[n][t2] = *(const short8*)(VTg + (size_t)((bb * 20 + hd) * 64 + n * 16 + cb) * 96 +
                                   t2 * 32 + kgu);

#pragma unroll
  for (int c = 0; c < 4; ++c) {
#pragma unroll
    for (int i2 = 0; i2 < 2; ++i2)
#pragma unroll
      for (int j = 0; j < 4; ++j)
#pragma unroll
        for (int r = 0; r < 4; ++r)
          Qc[(i2 * 16 + kq * 4 + r) * 72 + j * 16 + fr] =
              f2bf(acc[2 * c + i2][j][r] * QSCALE);
    short8 qf[2][2];
#pragma unroll
    for (int i2 = 0; i2 < 2; ++i2)
#pragma unroll
      for (int t2 = 0; t2 < 2; ++t2)
        qf[i2][t2] = *(const short8*)(Qc + (i2 * 16 + cb) * 72 + t2 * 32 + kgu);

    f32x4 sc[2][5];
    {
      f32x4 zf = {0.f, 0.f, 0.f, 0.f};
#pragma unroll
      for (int i2 = 0; i2 < 2; ++i2)
#pragma unroll
        for (int j = 0; j < 5; ++j) sc[i2][j] = zf;
    }
#pragma unroll
    for (int t2 = 0; t2 < 2; ++t2)
#pragma unroll
      for (int i2 = 0; i2 < 2; ++i2)
#pragma unroll
        for (int j = 0; j < 5; ++j)
          sc[i2][j] = __builtin_amdgcn_mfma_f32_16x16x32_bf16(
              qf[i2][t2], kf[j][t2], sc[i2][j], 0, 0, 0);

    float inv[2][4];
#pragma unroll
    for (int i2 = 0; i2 < 2; ++i2) {
#pragma unroll
      for (int r = 0; r < 4; ++r) {
        float sum = 0.f;
#pragma unroll
        for (int j = 0; j < 4; ++j) {
          float pv = exp2f(sc[i2][j][r]);
          sc[i2][j][r] = pv;
          sum += pv;
        }
        {
          float pv = (cb < 13) ? exp2f(sc[i2][4][r]) : 0.f;
          sc[i2][4][r] = pv;
          sum += pv;
        }
#pragma unroll
        for (int mk = 8; mk >= 1; mk >>= 1) sum += __shfl_xor(sum, mk, 64);
        inv[i2][r] = 1.f / sum;
      }
    }

#pragma unroll
    for (int i2 = 0; i2 < 2; ++i2)
#pragma unroll
      for (int j = 0; j < 5; ++j)
#pragma unroll
        for (int r = 0; r < 4; ++r)
          Pw[(i2 * 16 + kq * 4 + r) * 104 + j * 16 + cb] = f2bf(sc[i2][j][r]);

    f32x4 o[2][4];
    {
      f32x4 zf = {0.f, 0.f, 0.f, 0.f};
#pragma unroll
      for (int i2 = 0; i2 < 2; ++i2)
#pragma unroll
        for (int n = 0; n < 4; ++n) o[i2][n] = zf;
    }
#pragma unroll
    for (int t2 = 0; t2 < 3; ++t2) {
      short8 pf[2];
#pragma unroll
      for (int i2 = 0; i2 < 2; ++i2)
        pf[i2] = *(const short8*)(Pw + (i2 * 16 + cb) * 104 + t2 * 32 + kgu);
#pragma unroll
      for (int i2 = 0; i2 < 2; ++i2)
#pragma unroll
        for (int n = 0; n < 4; ++n)
          o[i2][n] = __builtin_amdgcn_mfma_f32_16x16x32_bf16(
              pf[i2], vf[n][t2], o[i2][n], 0, 0, 0);
    }

#pragma unroll
    for (int i2 = 0; i2 < 2; ++i2)
#pragma unroll
      for (int n = 0; n < 4; ++n)
#pragma unroll
        for (int r = 0; r < 4; ++r)
          Qc[(i2 * 16 + kq * 4 + r) * 72 + n * 16 + cb] =
              f2bf(o[i2][n][r] * inv[i2][r]);
    {
      const int lr2 = lane >> 3, lc2 = (lane & 7) * 8;
#pragma unroll
      for (int it = 0; it < 4; ++it) {
        const int rl = it * 8 + lr2;
        short8 v = *(const short8*)(Qc + rl * 72 + lc2);
        *(short8*)(Obuf + (size_t)(orow + c * 32 + rl) * 1280 + hd * 64 + lc2) = v;
      }
    }
  }
}

// ---------------- launch ----------------
extern "C" void kernel_launch(void* const* d_in, const int* in_sizes, int n_in,
                              void* d_out, int out_size, void* d_ws, size_t ws_size,
                              hipStream_t stream) {
  (void)in_sizes; (void)n_in; (void)out_size; (void)ws_size;
  const float* hs  = (const float*)d_in[0];
  const float* ehs = (const float*)d_in[1];
  const float* Wq  = (const float*)d_in[2];
  const float* Wk  = (const float*)d_in[3];
  const float* Wv  = (const float*)d_in[4];
  const float* Wo  = (const float*)d_in[5];
  const float* bo  = (const float*)d_in[6];
  const float* qd  = (const float*)d_in[7];
  const float* qu  = (const float*)d_in[8];
  const float* kd  = (const float*)d_in[9];
  const float* ku  = (const float*)d_in[10];
  const float* vd  = (const float*)d_in[11];
  const float* vu  = (const float*)d_in[12];
  const float* od  = (const float*)d_in[13];
  const float* ou  = (const float*)d_in[14];

  char* p = (char*)d_ws;
  u16* q_buf = (u16*)p;  p += (size_t)65536 * 1280 * 2;  // attn output (bf16)
  u16* wq_t  = (u16*)p;  p += (size_t)1280 * 1280 * 2;
  u16* wo_t  = (u16*)p;  p += (size_t)1280 * 1280 * 2;
  u16* wk_t  = (u16*)p;  p += (size_t)1280 * 768 * 2;
  u16* wv_t  = (u16*)p;  p += (size_t)1280 * 768 * 2;
  u16* ehs_b = (u16*)p;  p += (size_t)1280 * 768 * 2;
  u16* k_buf = (u16*)p;  p += (size_t)1280 * 1280 * 2;
  u16* vt    = (u16*)p;  p += (size_t)16 * 20 * 64 * 96 * 2;  // V^T [b][h][d][96]
  u16* hs_b  = (u16*)d_out;   // bf16 scratch in d_out; overwritten by final GEMM

  k_prepc<<<47520, 256, 0, stream>>>(hs, hs_b, ehs, ehs_b, vt,
                                     Wq, qd, qu, wq_t,
                                     Wk, kd, ku, wk_t,
                                     Wv, vd, vu, wv_t,
                                     Wo, od, ou, wo_t);

  k_gemmKV<<<dim3(10, 10, 2), 256, 0, stream>>>(ehs_b, wk_t, wv_t, k_buf, vt);

  k_gemm256qa<<<1280, 512, 0, stream>>>(hs_b, wq_t, k_buf, vt, q_buf);   // CONTROL structure

  k_gemm256h<<<1280, 512, 0, stream>>>(q_buf, wo_t, (float*)d_out, bo);  // EXPERIMENT: BK=32, 2 blk/CU
}

// Round 13
// 704.212 us; speedup vs baseline: 3.0374x; 3.0374x over previous
//
#include <hip/hip_runtime.h>
#include <hip/hip_bf16.h>
#include <stdint.h>

// ---------------- types / helpers ----------------
typedef unsigned short u16;
typedef __attribute__((ext_vector_type(8))) short short8;   // 8 bf16 (4 VGPRs)
typedef __attribute__((ext_vector_type(4))) float f32x4;

__device__ __forceinline__ u16 f2bf(float f) {  // RNE float->bf16
  union { float f; unsigned u; } v; v.f = f;
  unsigned r = v.u + 0x7fffu + ((v.u >> 16) & 1u);
  return (u16)(r >> 16);
}

__device__ __forceinline__ void g2lds16(const u16* g, u16* l) {
  // async global->LDS, 16B/lane; LDS dest = wave-uniform base + lane*16
  __builtin_amdgcn_global_load_lds(
      (const __attribute__((address_space(1))) uint32_t*)g,
      (__attribute__((address_space(3))) uint32_t*)l, 16, 0, 0);
}

#define BAR()   asm volatile("s_barrier" ::: "memory")
#define LGKM0() asm volatile("s_waitcnt lgkmcnt(0)" ::: "memory")
#define VM8()   asm volatile("s_waitcnt vmcnt(8)" ::: "memory")
#define VM0()   asm volatile("s_waitcnt vmcnt(0)" ::: "memory")
#define PRIO1() __builtin_amdgcn_s_setprio(1)
#define PRIO0() __builtin_amdgcn_s_setprio(0)

// Q pre-scale: 1/sqrt(64) * log2(e), folded into Q so attn uses exp2 directly
#define QSCALE 0.18033688f

// -------- merged prep: hs convert + ehs convert_pad + vt zero + 4x weight fusion --------
__global__ __launch_bounds__(256) void k_prepc(
    const float* __restrict__ hs, u16* __restrict__ hs_b,
    const float* __restrict__ ehs, u16* __restrict__ ehs_b,
    u16* __restrict__ vt,
    const float* __restrict__ Wq, const float* __restrict__ qd, const float* __restrict__ qu, u16* __restrict__ wq_t,
    const float* __restrict__ Wk, const float* __restrict__ kd, const float* __restrict__ ku, u16* __restrict__ wk_t,
    const float* __restrict__ Wv, const float* __restrict__ vd, const float* __restrict__ vu, u16* __restrict__ wv_t,
    const float* __restrict__ Wo, const float* __restrict__ od, const float* __restrict__ ou, u16* __restrict__ wo_t) {
  __shared__ float dn[64][65];
  __shared__ float up[64][17];
  int bid = blockIdx.x;

  if (bid < 40960) {   // hs f32 -> bf16
    int i = bid * 256 + threadIdx.x;
    const float4* p = (const float4*)(hs + (size_t)i * 8);
    float4 a = p[0], b = p[1];
    short8 o;
    o[0] = (short)f2bf(a.x); o[1] = (short)f2bf(a.y);
    o[2] = (short)f2bf(a.z); o[3] = (short)f2bf(a.w);
    o[4] = (short)f2bf(b.x); o[5] = (short)f2bf(b.y);
    o[6] = (short)f2bf(b.z); o[7] = (short)f2bf(b.w);
    *(short8*)(hs_b + (size_t)i * 8) = o;
    return;
  }
  bid -= 40960;
  if (bid < 480) {   // convert_pad: ehs
    int i = bid * 256 + threadIdx.x;
    short8 o;
    if (i < 118272) {
      const float4* p = (const float4*)(ehs + (size_t)i * 8);
      float4 a = p[0], b = p[1];
      o[0] = (short)f2bf(a.x); o[1] = (short)f2bf(a.y);
      o[2] = (short)f2bf(a.z); o[3] = (short)f2bf(a.w);
      o[4] = (short)f2bf(b.x); o[5] = (short)f2bf(b.y);
      o[6] = (short)f2bf(b.z); o[7] = (short)f2bf(b.w);
    } else {
#pragma unroll
      for (int e = 0; e < 8; ++e) o[e] = 0;
    }
    *(short8*)(ehs_b + (size_t)i * 8) = o;
    return;
  }
  bid -= 480;
  if (bid < 960) {   // zero vt (16*20*64*96 u16)
    int i = bid * 256 + threadIdx.x;
    short8 z;
#pragma unroll
    for (int e = 0; e < 8; ++e) z[e] = 0;
    *(short8*)(vt + (size_t)i * 8) = z;
    return;
  }
  bid -= 960;
  const float *W, *dng, *upg; u16* Wt; int K, bx, by;
  if (bid < 1600)      { W = Wq; dng = qd; upg = qu; Wt = wq_t; K = 1280; bx = bid % 20; by = bid / 20; }
  else if (bid < 2560) { bid -= 1600; W = Wk; dng = kd; upg = ku; Wt = wk_t; K = 768;  bx = bid % 12; by = bid / 12; }
  else if (bid < 3520) { bid -= 2560; W = Wv; dng = vd; upg = vu; Wt = wv_t; K = 768;  bx = bid % 12; by = bid / 12; }
  else                 { bid -= 3520; W = Wo; dng = od; upg = ou; Wt = wo_t; K = 1280; bx = bid % 20; by = bid / 20; }
  const int N = 1280;
  const int k0 = bx * 64, n0 = by * 16;
  const int kc = threadIdx.x & 63, ty = threadIdx.x >> 6;
  for (int c = threadIdx.x; c < 4096; c += 256)
    dn[c >> 6][c & 63] = dng[(size_t)(k0 + (c >> 6)) * 64 + (c & 63)];
  for (int c = threadIdx.x; c < 1024; c += 256)
    up[c >> 4][c & 15] = upg[(size_t)(c >> 4) * N + n0 + (c & 15)];
  __syncthreads();
  float acc[4];
#pragma unroll
  for (int e = 0; e < 4; ++e)
    acc[e] = W[(size_t)(k0 + kc) * N + n0 + ty * 4 + e];
#pragma unroll 16
  for (int r = 0; r < 64; ++r) {
    float d = dn[kc][r];
#pragma unroll
    for (int e = 0; e < 4; ++e) acc[e] += d * up[r][ty * 4 + e];
  }
#pragma unroll
  for (int e = 0; e < 4; ++e)
    Wt[(size_t)(n0 + ty * 4 + e) * K + k0 + kc] = f2bf(acc[e]);
}

// ---------------- K/V projections (z=0: K row-major; z=1: V transposed to vt) ----------------
__global__ __launch_bounds__(256) void k_gemmKV(const u16* __restrict__ A,
                                                const u16* __restrict__ BtK,
                                                const u16* __restrict__ BtV,
                                                u16* __restrict__ CK,
                                                u16* __restrict__ VT) {
  constexpr int N = 1280, K = 768;
  const u16* Bt = blockIdx.z ? BtV : BtK;
  __shared__ __align__(16) u16 As[128 * 32];
  __shared__ __align__(16) u16 Bs[128 * 32];
  const int tid = threadIdx.x, lane = tid & 63, w = tid >> 6;
  const int n0 = blockIdx.x * 128, m0 = blockIdx.y * 128;
  const int wm = (w >> 1) * 64, wn = (w & 1) * 64;

  f32x4 acc[4][4];
  f32x4 zf = {0.f, 0.f, 0.f, 0.f};
#pragma unroll
  for (int i = 0; i < 4; ++i)
#pragma unroll
    for (int j = 0; j < 4; ++j) acc[i][j] = zf;

  const int c0 = w, c1 = w + 4;
  const int rA0 = c0 * 16 + (lane >> 2), rA1 = c1 * 16 + (lane >> 2);
  const int kp = (lane & 3) * 8;
  const u16* gA0 = A + (size_t)(m0 + rA0) * K + kp;
  const u16* gA1 = A + (size_t)(m0 + rA1) * K + kp;
  const u16* gB0 = Bt + (size_t)(n0 + rA0) * K + kp;
  const u16* gB1 = Bt + (size_t)(n0 + rA1) * K + kp;
  u16* lA0 = As + c0 * 512;  u16* lA1 = As + c1 * 512;
  u16* lB0 = Bs + c0 * 512;  u16* lB1 = Bs + c1 * 512;

  const int fr = lane & 15, kg = (lane >> 4) * 8;

  for (int k0 = 0; k0 < K; k0 += 32) {
    g2lds16(gA0 + k0, lA0);
    g2lds16(gA1 + k0, lA1);
    g2lds16(gB0 + k0, lB0);
    g2lds16(gB1 + k0, lB1);
    __syncthreads();
    short8 af[4], bf[4];
#pragma unroll
    for (int i = 0; i < 4; ++i)
      af[i] = *(const short8*)(As + (wm + i * 16 + fr) * 32 + kg);
#pragma unroll
    for (int j = 0; j < 4; ++j)
      bf[j] = *(const short8*)(Bs + (wn + j * 16 + fr) * 32 + kg);
#pragma unroll
    for (int i = 0; i < 4; ++i)
#pragma unroll
      for (int j = 0; j < 4; ++j)
        acc[i][j] = __builtin_amdgcn_mfma_f32_16x16x32_bf16(af[i], bf[j], acc[i][j], 0, 0, 0);
    __syncthreads();
  }

  const int rb = (lane >> 4) * 4;
  if (blockIdx.z == 0) {
#pragma unroll
    for (int i = 0; i < 4; ++i)
#pragma unroll
      for (int j = 0; j < 4; ++j) {
        int col = n0 + wn + j * 16 + fr;
#pragma unroll
        for (int r = 0; r < 4; ++r) {
          int row = m0 + wm + i * 16 + rb + r;
          CK[(size_t)row * N + col] = f2bf(acc[i][j][r]);
        }
      }
  } else {
#pragma unroll
    for (int i = 0; i < 4; ++i)
#pragma unroll
      for (int j = 0; j < 4; ++j) {
        int col = n0 + wn + j * 16 + fr;
        int h = col >> 6, d = col & 63;
#pragma unroll
        for (int r = 0; r < 4; ++r) {
          int row = m0 + wm + i * 16 + rb + r;
          if (row < 1232) {
            int b2 = row / 77;
            int s2 = row - b2 * 77;
            VT[(size_t)((b2 * 20 + h) * 64 + d) * 96 + s2] = f2bf(acc[i][j][r]);
          }
        }
      }
  }
}

// ================= shared pieces for the 256x256 kernels =================
#define GEMM256_COMMON()                                                       \
  constexpr int K = 1280;                                                      \
  constexpr int N = 1280;                                                      \
  __shared__ __align__(16) u16 lds[2][2][2][128 * 64];                         \
  const int lane = threadIdx.x & 63, w = threadIdx.x >> 6;                     \
  const int bid = blockIdx.x;                                                  \
  const int tile = (bid & 7) * 160 + (bid >> 3);                               \
  const int n0 = (tile % 5) * 256, m0 = (tile / 5) * 256;                      \
  const int l0 = w * 2;                                                        \
  const int fr = lane & 15;                                                    \
  const int q16b = (lane >> 4) * 16;                                           \
  const int xr = (fr & 7) << 4;                                                \
  const int cT0 = ((0 + q16b) ^ xr) >> 1;                                      \
  const int cT1 = ((64 + q16b) ^ xr) >> 1;                                     \
  const int ha = w >> 2;                                                       \
  const int hb = (w & 3) >> 1;                                                 \
  const int rB0 = (w & 1) * 64;

#define GSRC_INIT(A_, Bt_)                                                     \
  const u16* gsrc[4][2];                                                       \
  _Pragma("unroll") for (int s2 = 0; s2 < 4; ++s2) {                           \
    const int side = s2 >> 1, h = s2 & 1;                                      \
    _Pragma("unroll") for (int l = 0; l < 2; ++l) {                            \
      const int o = (l0 + l) * 1024 + lane * 16;                               \
      const int row = o >> 7;                                                  \
      const int scol = (o & 127) ^ ((row & 7) << 4);                           \
      const u16* base = side ? ((Bt_) + (size_t)(n0 + h * 128 + row) * K)      \
                             : ((A_) + (size_t)(m0 + h * 128 + row) * K);      \
      gsrc[s2][l] = base + (scol >> 1);                                        \
    }                                                                          \
  }

#define STAGE_HALF(P, SIDE, H, KT)                                             \
  do {                                                                         \
    g2lds16(gsrc[(SIDE) * 2 + (H)][0] + (KT) * 64,                             \
            &lds[P][SIDE][H][(l0 + 0) * 512]);                                 \
    g2lds16(gsrc[(SIDE) * 2 + (H)][1] + (KT) * 64,                             \
            &lds[P][SIDE][H][(l0 + 1) * 512]);                                 \
  } while (0)

#define STAGE_FULL(P, KT)                                                      \
  do {                                                                         \
    STAGE_HALF(P, 0, 0, KT); STAGE_HALF(P, 0, 1, KT);                          \
    STAGE_HALF(P, 1, 0, KT); STAGE_HALF(P, 1, 1, KT);                          \
  } while (0)

#define LOAD_AF(P, IB)                                                         \
  do {                                                                         \
    _Pragma("unroll") for (int ii = 0; ii < 4; ++ii) {                         \
      const u16* rp = &lds[P][0][ha][(((IB) + ii) * 16 + fr) * 64];            \
      af[ii][0] = *(const short8*)(rp + cT0);                                  \
      af[ii][1] = *(const short8*)(rp + cT1);                                  \
    }                                                                          \
  } while (0)

#define LOAD_BF(P, JB)                                                         \
  do {                                                                         \
    _Pragma("unroll") for (int jj = 0; jj < 2; ++jj) {                         \
      const u16* rp = &lds[P][1][hb][(rB0 + ((JB) + jj) * 16 + fr) * 64];      \
      bf[(JB) + jj][0] = *(const short8*)(rp + cT0);                           \
      bf[(JB) + jj][1] = *(const short8*)(rp + cT1);                           \
    }                                                                          \
  } while (0)

#define MFMA_Q(IO, JB)                                                         \
  do {                                                                         \
    _Pragma("unroll") for (int t = 0; t < 2; ++t)                              \
        _Pragma("unroll") for (int ii = 0; ii < 4; ++ii)                       \
            _Pragma("unroll") for (int jj = 0; jj < 2; ++jj)                   \
                acc[(IO) + ii][(JB) + jj] =                                    \
        __builtin_amdgcn_mfma_f32_16x16x32_bf16(                               \
            af[ii][t], bf[(JB) + jj][t], acc[(IO) + ii][(JB) + jj], 0, 0, 0);  \
  } while (0)

#define ACC_ZERO()                                                             \
  do {                                                                         \
    f32x4 zf = {0.f, 0.f, 0.f, 0.f};                                           \
    _Pragma("unroll") for (int i = 0; i < 8; ++i)                              \
        _Pragma("unroll") for (int j = 0; j < 4; ++j) acc[i][j] = zf;          \
  } while (0)

#define GEMM256_MAINLOOP()                                                     \
  do {                                                                         \
    STAGE_FULL(0, 0);                                                          \
    STAGE_FULL(1, 1);                                                          \
    VM8();                                                                     \
    BAR();                                                                     \
    for (int t = 0; t < 20; ++t) {                                             \
      const int P = t & 1;                                                     \
      LOAD_AF(P, 0);                                                           \
      LOAD_BF(P, 0);                                                           \
      LOAD_BF(P, 2);                                                           \
      MFMA_Q(0, 0);                                                            \
      MFMA_Q(0, 2);                                                            \
      LOAD_AF(P, 4);                                                           \
      MFMA_Q(4, 2);                                                            \
      LGKM0();                                                                 \
      BAR();                                                                   \
      if (t < 18) STAGE_FULL(P, t + 2);                                        \
      PRIO1(); MFMA_Q(4, 0); PRIO0();                                          \
      if (t < 18) { VM8(); } else { VM0(); }                                   \
      BAR();                                                                   \
    }                                                                          \
  } while (0)

// ---------------- O-GEMM: fused-tile, f32 out + bias (proven R3/R11 config) ----------------
__global__ __launch_bounds__(512, 2) void k_gemm256f(const u16* __restrict__ A,
                                                     const u16* __restrict__ Bt,
                                                     float* __restrict__ Cout,
                                                     const float* __restrict__ bias) {
  GEMM256_COMMON();
  GSRC_INIT(A, Bt);
  short8 af[4][2], bf[4][2];
  f32x4 acc[8][4];
  ACC_ZERO();
  GEMM256_MAINLOOP();

  const int rb = (lane >> 4) * 4;
  const int orow = m0 + (w >> 2) * 128;
  const int ocol = n0 + (w & 3) * 64;
#pragma unroll
  for (int i = 0; i < 8; ++i)
#pragma unroll
    for (int j = 0; j < 4; ++j) {
      const int col = ocol + j * 16 + fr;
      const float bj = bias[col];
#pragma unroll
      for (int r = 0; r < 4; ++r)
        Cout[(size_t)(orow + i * 16 + rb + r) * N + col] = acc[i][j][r] + bj;
    }
}

// ---------------- Q-GEMM + FUSED ATTENTION (R11 proven) ----------------
__global__ __launch_bounds__(512, 1) void k_gemm256qa(const u16* __restrict__ A,
                                                      const u16* __restrict__ Bt,
                                                      const u16* __restrict__ Kbuf,
                                                      const u16* __restrict__ VTg,
                                                      u16* __restrict__ Obuf) {
  GEMM256_COMMON();
  GSRC_INIT(A, Bt);
  short8 af[4][2], bf[4][2];
  f32x4 acc[8][4];
  ACC_ZERO();
  GEMM256_MAINLOOP();

  const int bb = (tile / 5) >> 4;             // batch
  const int hd = (tile % 5) * 4 + (w & 3);    // head
  const int orow = m0 + (w >> 2) * 128;
  const int cb = fr, kq = lane >> 4, kgu = kq * 8;

  u16* ldsb = (u16*)lds;
  u16* Qc = ldsb + w * 2304;                  // [32][72]
  u16* Pw = ldsb + 8 * 2304 + w * 3328;       // [32][104]

  {
    short8 zz;
#pragma unroll
    for (int e = 0; e < 8; ++e) zz[e] = 0;
    *(short8*)(Pw + (lane >> 1) * 104 + 80 + (lane & 1) * 8) = zz;
  }

  short8 kf[5][2];
#pragma unroll
  for (int j = 0; j < 5; ++j)
#pragma unroll
    for (int t2 = 0; t2 < 2; ++t2)
      kf[j][t2] = *(const short8*)(Kbuf + (size_t)(bb * 77 + j * 16 + cb) * 1280 +
                                   hd * 64 + t2 * 32 + kgu);
  short8 vf[4][3];
#pragma unroll
  for (int n = 0; n < 4; ++n)
#pragma unroll
    for (int t2 = 0; t2 < 3; ++t2)
      vf[n][t2] = *(const short8*)(VTg + (size_t)((bb * 20 + hd) * 64 + n * 16 + cb) * 96 +
                                   t2 * 32 + kgu);

#pragma unroll
  for (int c = 0; c < 4; ++c) {
#pragma unroll
    for (int i2 = 0; i2 < 2; ++i2)
#pragma unroll
      for (int j = 0; j < 4; ++j)
#pragma unroll
        for (int r = 0; r < 4; ++r)
          Qc[(i2 * 16 + kq * 4 + r) * 72 + j * 16 + fr] =
              f2bf(acc[2 * c + i2][j][r] * QSCALE);
    short8 qf[2][2];
#pragma unroll
    for (int i2 = 0; i2 < 2; ++i2)
#pragma unroll
      for (int t2 = 0; t2 < 2; ++t2)
        qf[i2][t2] = *(const short8*)(Qc + (i2 * 16 + cb) * 72 + t2 * 32 + kgu);

    f32x4 sc[2][5];
    {
      f32x4 zf = {0.f, 0.f, 0.f, 0.f};
#pragma unroll
      for (int i2 = 0; i2 < 2; ++i2)
#pragma unroll
        for (int j = 0; j < 5; ++j) sc[i2][j] = zf;
    }
#pragma unroll
    for (int t2 = 0; t2 < 2; ++t2)
#pragma unroll
      for (int i2 = 0; i2 < 2; ++i2)
#pragma unroll
        for (int j = 0; j < 5; ++j)
          sc[i2][j] = __builtin_amdgcn_mfma_f32_16x16x32_bf16(
              qf[i2][t2], kf[j][t2], sc[i2][j], 0, 0, 0);

    float inv[2][4];
#pragma unroll
    for (int i2 = 0; i2 < 2; ++i2) {
#pragma unroll
      for (int r = 0; r < 4; ++r) {
        float sum = 0.f;
#pragma unroll
        for (int j = 0; j < 4; ++j) {
          float pv = exp2f(sc[i2][j][r]);
          sc[i2][j][r] = pv;
          sum += pv;
        }
        {
          float pv = (cb < 13) ? exp2f(sc[i2][4][r]) : 0.f;
          sc[i2][4][r] = pv;
          sum += pv;
        }
#pragma unroll
        for (int mk = 8; mk >= 1; mk >>= 1) sum += __shfl_xor(sum, mk, 64);
        inv[i2][r] = 1.f / sum;
      }
    }

#pragma unroll
    for (int i2 = 0; i2 < 2; ++i2)
#pragma unroll
      for (int j = 0; j < 5; ++j)
#pragma unroll
        for (int r = 0; r < 4; ++r)
          Pw[(i2 * 16 + kq * 4 + r) * 104 + j * 16 + cb] = f2bf(sc[i2][j][r]);

    f32x4 o[2][4];
    {
      f32x4 zf = {0.f, 0.f, 0.f, 0.f};
#pragma unroll
      for (int i2 = 0; i2 < 2; ++i2)
#pragma unroll
        for (int n = 0; n < 4; ++n) o[i2][n] = zf;
    }
#pragma unroll
    for (int t2 = 0; t2 < 3; ++t2) {
      short8 pf[2];
#pragma unroll
      for (int i2 = 0; i2 < 2; ++i2)
        pf[i2] = *(const short8*)(Pw + (i2 * 16 + cb) * 104 + t2 * 32 + kgu);
#pragma unroll
      for (int i2 = 0; i2 < 2; ++i2)
#pragma unroll
        for (int n = 0; n < 4; ++n)
          o[i2][n] = __builtin_amdgcn_mfma_f32_16x16x32_bf16(
              pf[i2], vf[n][t2], o[i2][n], 0, 0, 0);
    }

#pragma unroll
    for (int i2 = 0; i2 < 2; ++i2)
#pragma unroll
      for (int n = 0; n < 4; ++n)
#pragma unroll
        for (int r = 0; r < 4; ++r)
          Qc[(i2 * 16 + kq * 4 + r) * 72 + n * 16 + cb] =
              f2bf(o[i2][n][r] * inv[i2][r]);
    {
      const int lr2 = lane >> 3, lc2 = (lane & 7) * 8;
#pragma unroll
      for (int it = 0; it < 4; ++it) {
        const int rl = it * 8 + lr2;
        short8 v = *(const short8*)(Qc + rl * 72 + lc2);
        *(short8*)(Obuf + (size_t)(orow + c * 32 + rl) * 1280 + hd * 64 + lc2) = v;
      }
    }
  }
}

// ---------------- launch ----------------
extern "C" void kernel_launch(void* const* d_in, const int* in_sizes, int n_in,
                              void* d_out, int out_size, void* d_ws, size_t ws_size,
                              hipStream_t stream) {
  (void)in_sizes; (void)n_in; (void)out_size; (void)ws_size;
  const float* hs  = (const float*)d_in[0];
  const float* ehs = (const float*)d_in[1];
  const float* Wq  = (const float*)d_in[2];
  const float* Wk  = (const float*)d_in[3];
  const float* Wv  = (const float*)d_in[4];
  const float* Wo  = (const float*)d_in[5];
  const float* bo  = (const float*)d_in[6];
  const float* qd  = (const float*)d_in[7];
  const float* qu  = (const float*)d_in[8];
  const float* kd  = (const float*)d_in[9];
  const float* ku  = (const float*)d_in[10];
  const float* vd  = (const float*)d_in[11];
  const float* vu  = (const float*)d_in[12];
  const float* od  = (const float*)d_in[13];
  const float* ou  = (const float*)d_in[14];

  char* p = (char*)d_ws;
  u16* q_buf = (u16*)p;  p += (size_t)65536 * 1280 * 2;  // attn output (bf16)
  u16* wq_t  = (u16*)p;  p += (size_t)1280 * 1280 * 2;
  u16* wo_t  = (u16*)p;  p += (size_t)1280 * 1280 * 2;
  u16* wk_t  = (u16*)p;  p += (size_t)1280 * 768 * 2;
  u16* wv_t  = (u16*)p;  p += (size_t)1280 * 768 * 2;
  u16* ehs_b = (u16*)p;  p += (size_t)1280 * 768 * 2;
  u16* k_buf = (u16*)p;  p += (size_t)1280 * 1280 * 2;
  u16* vt    = (u16*)p;  p += (size_t)16 * 20 * 64 * 96 * 2;  // V^T [b][h][d][96]
  u16* hs_b  = (u16*)d_out;   // bf16 scratch in d_out; overwritten by final GEMM

  k_prepc<<<47520, 256, 0, stream>>>(hs, hs_b, ehs, ehs_b, vt,
                                     Wq, qd, qu, wq_t,
                                     Wk, kd, ku, wk_t,
                                     Wv, vd, vu, wv_t,
                                     Wo, od, ou, wo_t);

  k_gemmKV<<<dim3(10, 10, 2), 256, 0, stream>>>(ehs_b, wk_t, wv_t, k_buf, vt);

  k_gemm256qa<<<1280, 512, 0, stream>>>(hs_b, wq_t, k_buf, vt, q_buf);   // Q-GEMM + attn

  k_gemm256f<<<1280, 512, 0, stream>>>(q_buf, wo_t, (float*)d_out, bo);  // O-GEMM
}

// Round 14
// 696.694 us; speedup vs baseline: 3.0702x; 1.0108x over previous
//
#include <hip/hip_runtime.h>
#include <hip/hip_bf16.h>
#include <stdint.h>

// ---------------- types / helpers ----------------
typedef unsigned short u16;
typedef __attribute__((ext_vector_type(8))) short short8;   // 8 bf16 (4 VGPRs)
typedef __attribute__((ext_vector_type(4))) float f32x4;

__device__ __forceinline__ u16 f2bf(float f) {  // RNE float->bf16
  union { float f; unsigned u; } v; v.f = f;
  unsigned r = v.u + 0x7fffu + ((v.u >> 16) & 1u);
  return (u16)(r >> 16);
}

__device__ __forceinline__ void g2lds16(const u16* g, u16* l) {
  // async global->LDS, 16B/lane; LDS dest = wave-uniform base + lane*16
  __builtin_amdgcn_global_load_lds(
      (const __attribute__((address_space(1))) uint32_t*)g,
      (__attribute__((address_space(3))) uint32_t*)l, 16, 0, 0);
}

#define BAR()   asm volatile("s_barrier" ::: "memory")
#define LGKM0() asm volatile("s_waitcnt lgkmcnt(0)" ::: "memory")
#define VM8()   asm volatile("s_waitcnt vmcnt(8)" ::: "memory")
#define VM0()   asm volatile("s_waitcnt vmcnt(0)" ::: "memory")
#define PRIO1() __builtin_amdgcn_s_setprio(1)
#define PRIO0() __builtin_amdgcn_s_setprio(0)

// Q pre-scale: 1/sqrt(64) * log2(e), folded into Q so attn uses exp2 directly
#define QSCALE 0.18033688f

// -------- merged prep: hs convert + ehs convert_pad + vt zero + 4x weight fusion --------
__global__ __launch_bounds__(256) void k_prepc(
    const float* __restrict__ hs, u16* __restrict__ hs_b,
    const float* __restrict__ ehs, u16* __restrict__ ehs_b,
    u16* __restrict__ vt,
    const float* __restrict__ Wq, const float* __restrict__ qd, const float* __restrict__ qu, u16* __restrict__ wq_t,
    const float* __restrict__ Wk, const float* __restrict__ kd, const float* __restrict__ ku, u16* __restrict__ wk_t,
    const float* __restrict__ Wv, const float* __restrict__ vd, const float* __restrict__ vu, u16* __restrict__ wv_t,
    const float* __restrict__ Wo, const float* __restrict__ od, const float* __restrict__ ou, u16* __restrict__ wo_t) {
  __shared__ float dn[64][65];
  __shared__ float up[64][17];
  int bid = blockIdx.x;

  if (bid < 40960) {   // hs f32 -> bf16
    int i = bid * 256 + threadIdx.x;
    const float4* p = (const float4*)(hs + (size_t)i * 8);
    float4 a = p[0], b = p[1];
    short8 o;
    o[0] = (short)f2bf(a.x); o[1] = (short)f2bf(a.y);
    o[2] = (short)f2bf(a.z); o[3] = (short)f2bf(a.w);
    o[4] = (short)f2bf(b.x); o[5] = (short)f2bf(b.y);
    o[6] = (short)f2bf(b.z); o[7] = (short)f2bf(b.w);
    *(short8*)(hs_b + (size_t)i * 8) = o;
    return;
  }
  bid -= 40960;
  if (bid < 480) {   // convert_pad: ehs
    int i = bid * 256 + threadIdx.x;
    short8 o;
    if (i < 118272) {
      const float4* p = (const float4*)(ehs + (size_t)i * 8);
      float4 a = p[0], b = p[1];
      o[0] = (short)f2bf(a.x); o[1] = (short)f2bf(a.y);
      o[2] = (short)f2bf(a.z); o[3] = (short)f2bf(a.w);
      o[4] = (short)f2bf(b.x); o[5] = (short)f2bf(b.y);
      o[6] = (short)f2bf(b.z); o[7] = (short)f2bf(b.w);
    } else {
#pragma unroll
      for (int e = 0; e < 8; ++e) o[e] = 0;
    }
    *(short8*)(ehs_b + (size_t)i * 8) = o;
    return;
  }
  bid -= 480;
  if (bid < 960) {   // zero vt (16*20*64*96 u16)
    int i = bid * 256 + threadIdx.x;
    short8 z;
#pragma unroll
    for (int e = 0; e < 8; ++e) z[e] = 0;
    *(short8*)(vt + (size_t)i * 8) = z;
    return;
  }
  bid -= 960;
  const float *W, *dng, *upg; u16* Wt; int K, bx, by;
  if (bid < 1600)      { W = Wq; dng = qd; upg = qu; Wt = wq_t; K = 1280; bx = bid % 20; by = bid / 20; }
  else if (bid < 2560) { bid -= 1600; W = Wk; dng = kd; upg = ku; Wt = wk_t; K = 768;  bx = bid % 12; by = bid / 12; }
  else if (bid < 3520) { bid -= 2560; W = Wv; dng = vd; upg = vu; Wt = wv_t; K = 768;  bx = bid % 12; by = bid / 12; }
  else                 { bid -= 3520; W = Wo; dng = od; upg = ou; Wt = wo_t; K = 1280; bx = bid % 20; by = bid / 20; }
  const int N = 1280;
  const int k0 = bx * 64, n0 = by * 16;
  const int kc = threadIdx.x & 63, ty = threadIdx.x >> 6;
  for (int c = threadIdx.x; c < 4096; c += 256)
    dn[c >> 6][c & 63] = dng[(size_t)(k0 + (c >> 6)) * 64 + (c & 63)];
  for (int c = threadIdx.x; c < 1024; c += 256)
    up[c >> 4][c & 15] = upg[(size_t)(c >> 4) * N + n0 + (c & 15)];
  __syncthreads();
  float acc[4];
#pragma unroll
  for (int e = 0; e < 4; ++e)
    acc[e] = W[(size_t)(k0 + kc) * N + n0 + ty * 4 + e];
#pragma unroll 16
  for (int r = 0; r < 64; ++r) {
    float d = dn[kc][r];
#pragma unroll
    for (int e = 0; e < 4; ++e) acc[e] += d * up[r][ty * 4 + e];
  }
#pragma unroll
  for (int e = 0; e < 4; ++e)
    Wt[(size_t)(n0 + ty * 4 + e) * K + k0 + kc] = f2bf(acc[e]);
}

// ---------------- K/V projections (z=0: K row-major; z=1: V transposed to vt) ----------------
__global__ __launch_bounds__(256) void k_gemmKV(const u16* __restrict__ A,
                                                const u16* __restrict__ BtK,
                                                const u16* __restrict__ BtV,
                                                u16* __restrict__ CK,
                                                u16* __restrict__ VT) {
  constexpr int N = 1280, K = 768;
  const u16* Bt = blockIdx.z ? BtV : BtK;
  __shared__ __align__(16) u16 As[128 * 32];
  __shared__ __align__(16) u16 Bs[128 * 32];
  const int tid = threadIdx.x, lane = tid & 63, w = tid >> 6;
  const int n0 = blockIdx.x * 128, m0 = blockIdx.y * 128;
  const int wm = (w >> 1) * 64, wn = (w & 1) * 64;

  f32x4 acc[4][4];
  f32x4 zf = {0.f, 0.f, 0.f, 0.f};
#pragma unroll
  for (int i = 0; i < 4; ++i)
#pragma unroll
    for (int j = 0; j < 4; ++j) acc[i][j] = zf;

  const int c0 = w, c1 = w + 4;
  const int rA0 = c0 * 16 + (lane >> 2), rA1 = c1 * 16 + (lane >> 2);
  const int kp = (lane & 3) * 8;
  const u16* gA0 = A + (size_t)(m0 + rA0) * K + kp;
  const u16* gA1 = A + (size_t)(m0 + rA1) * K + kp;
  const u16* gB0 = Bt + (size_t)(n0 + rA0) * K + kp;
  const u16* gB1 = Bt + (size_t)(n0 + rA1) * K + kp;
  u16* lA0 = As + c0 * 512;  u16* lA1 = As + c1 * 512;
  u16* lB0 = Bs + c0 * 512;  u16* lB1 = Bs + c1 * 512;

  const int fr = lane & 15, kg = (lane >> 4) * 8;

  for (int k0 = 0; k0 < K; k0 += 32) {
    g2lds16(gA0 + k0, lA0);
    g2lds16(gA1 + k0, lA1);
    g2lds16(gB0 + k0, lB0);
    g2lds16(gB1 + k0, lB1);
    __syncthreads();
    short8 af[4], bf[4];
#pragma unroll
    for (int i = 0; i < 4; ++i)
      af[i] = *(const short8*)(As + (wm + i * 16 + fr) * 32 + kg);
#pragma unroll
    for (int j = 0; j < 4; ++j)
      bf[j] = *(const short8*)(Bs + (wn + j * 16 + fr) * 32 + kg);
#pragma unroll
    for (int i = 0; i < 4; ++i)
#pragma unroll
      for (int j = 0; j < 4; ++j)
        acc[i][j] = __builtin_amdgcn_mfma_f32_16x16x32_bf16(af[i], bf[j], acc[i][j], 0, 0, 0);
    __syncthreads();
  }

  const int rb = (lane >> 4) * 4;
  if (blockIdx.z == 0) {
#pragma unroll
    for (int i = 0; i < 4; ++i)
#pragma unroll
      for (int j = 0; j < 4; ++j) {
        int col = n0 + wn + j * 16 + fr;
#pragma unroll
        for (int r = 0; r < 4; ++r) {
          int row = m0 + wm + i * 16 + rb + r;
          CK[(size_t)row * N + col] = f2bf(acc[i][j][r]);
        }
      }
  } else {
#pragma unroll
    for (int i = 0; i < 4; ++i)
#pragma unroll
      for (int j = 0; j < 4; ++j) {
        int col = n0 + wn + j * 16 + fr;
        int h = col >> 6, d = col & 63;
#pragma unroll
        for (int r = 0; r < 4; ++r) {
          int row = m0 + wm + i * 16 + rb + r;
          if (row < 1232) {
            int b2 = row / 77;
            int s2 = row - b2 * 77;
            VT[(size_t)((b2 * 20 + h) * 64 + d) * 96 + s2] = f2bf(acc[i][j][r]);
          }
        }
      }
  }
}

// ================= shared pieces for the 256x256 kernels =================
// FLIPM=1 reverses the m-panel order (L3 producer->consumer timing): per-XCD
// contiguity preserved; pure bijection.
#define GEMM256_COMMON(FLIPM)                                                  \
  constexpr int K = 1280;                                                      \
  constexpr int N = 1280;                                                      \
  __shared__ __align__(16) u16 lds[2][2][2][128 * 64];                         \
  const int lane = threadIdx.x & 63, w = threadIdx.x >> 6;                     \
  const int bid = blockIdx.x;                                                  \
  const int tile = (bid & 7) * 160 + (bid >> 3);                               \
  const int mpan = (FLIPM) ? (255 - tile / 5) : (tile / 5);                    \
  const int n0 = (tile % 5) * 256, m0 = mpan * 256;                            \
  const int l0 = w * 2;                                                        \
  const int fr = lane & 15;                                                    \
  const int q16b = (lane >> 4) * 16;                                           \
  const int xr = (fr & 7) << 4;                                                \
  const int cT0 = ((0 + q16b) ^ xr) >> 1;                                      \
  const int cT1 = ((64 + q16b) ^ xr) >> 1;                                     \
  const int ha = w >> 2;                                                       \
  const int hb = (w & 3) >> 1;                                                 \
  const int rB0 = (w & 1) * 64;

#define GSRC_INIT(A_, Bt_)                                                     \
  const u16* gsrc[4][2];                                                       \
  _Pragma("unroll") for (int s2 = 0; s2 < 4; ++s2) {                           \
    const int side = s2 >> 1, h = s2 & 1;                                      \
    _Pragma("unroll") for (int l = 0; l < 2; ++l) {                            \
      const int o = (l0 + l) * 1024 + lane * 16;                               \
      const int row = o >> 7;                                                  \
      const int scol = (o & 127) ^ ((row & 7) << 4);                           \
      const u16* base = side ? ((Bt_) + (size_t)(n0 + h * 128 + row) * K)      \
                             : ((A_) + (size_t)(m0 + h * 128 + row) * K);      \
      gsrc[s2][l] = base + (scol >> 1);                                        \
    }                                                                          \
  }

#define STAGE_HALF(P, SIDE, H, KT)                                             \
  do {                                                                         \
    g2lds16(gsrc[(SIDE) * 2 + (H)][0] + (KT) * 64,                             \
            &lds[P][SIDE][H][(l0 + 0) * 512]);                                 \
    g2lds16(gsrc[(SIDE) * 2 + (H)][1] + (KT) * 64,                             \
            &lds[P][SIDE][H][(l0 + 1) * 512]);                                 \
  } while (0)

#define STAGE_FULL(P, KT)                                                      \
  do {                                                                         \
    STAGE_HALF(P, 0, 0, KT); STAGE_HALF(P, 0, 1, KT);                          \
    STAGE_HALF(P, 1, 0, KT); STAGE_HALF(P, 1, 1, KT);                          \
  } while (0)

#define LOAD_AF(P, IB)                                                         \
  do {                                                                         \
    _Pragma("unroll") for (int ii = 0; ii < 4; ++ii) {                         \
      const u16* rp = &lds[P][0][ha][(((IB) + ii) * 16 + fr) * 64];            \
      af[ii][0] = *(const short8*)(rp + cT0);                                  \
      af[ii][1] = *(const short8*)(rp + cT1);                                  \
    }                                                                          \
  } while (0)

#define LOAD_BF(P, JB)                                                         \
  do {                                                                         \
    _Pragma("unroll") for (int jj = 0; jj < 2; ++jj) {                         \
      const u16* rp = &lds[P][1][hb][(rB0 + ((JB) + jj) * 16 + fr) * 64];      \
      bf[(JB) + jj][0] = *(const short8*)(rp + cT0);                           \
      bf[(JB) + jj][1] = *(const short8*)(rp + cT1);                           \
    }                                                                          \
  } while (0)

#define MFMA_Q(IO, JB)                                                         \
  do {                                                                         \
    _Pragma("unroll") for (int t = 0; t < 2; ++t)                              \
        _Pragma("unroll") for (int ii = 0; ii < 4; ++ii)                       \
            _Pragma("unroll") for (int jj = 0; jj < 2; ++jj)                   \
                acc[(IO) + ii][(JB) + jj] =                                    \
        __builtin_amdgcn_mfma_f32_16x16x32_bf16(                               \
            af[ii][t], bf[(JB) + jj][t], acc[(IO) + ii][(JB) + jj], 0, 0, 0);  \
  } while (0)

#define ACC_ZERO()                                                             \
  do {                                                                         \
    f32x4 zf = {0.f, 0.f, 0.f, 0.f};                                           \
    _Pragma("unroll") for (int i = 0; i < 8; ++i)                              \
        _Pragma("unroll") for (int j = 0; j < 4; ++j) acc[i][j] = zf;          \
  } while (0)

#define GEMM256_MAINLOOP()                                                     \
  do {                                                                         \
    STAGE_FULL(0, 0);                                                          \
    STAGE_FULL(1, 1);                                                          \
    VM8();                                                                     \
    BAR();                                                                     \
    for (int t = 0; t < 20; ++t) {                                             \
      const int P = t & 1;                                                     \
      LOAD_AF(P, 0);                                                           \
      LOAD_BF(P, 0);                                                           \
      LOAD_BF(P, 2);                                                           \
      MFMA_Q(0, 0);                                                            \
      MFMA_Q(0, 2);                                                            \
      LOAD_AF(P, 4);                                                           \
      MFMA_Q(4, 2);                                                            \
      LGKM0();                                                                 \
      BAR();                                                                   \
      if (t < 18) STAGE_FULL(P, t + 2);                                        \
      PRIO1(); MFMA_Q(4, 0); PRIO0();                                          \
      if (t < 18) { VM8(); } else { VM0(); }                                   \
      BAR();                                                                   \
    }                                                                          \
  } while (0)

// ---------------- O-GEMM: fused-tile, f32 out + bias (m-ascending) ----------------
__global__ __launch_bounds__(512, 2) void k_gemm256f(const u16* __restrict__ A,
                                                     const u16* __restrict__ Bt,
                                                     float* __restrict__ Cout,
                                                     const float* __restrict__ bias) {
  GEMM256_COMMON(0);
  GSRC_INIT(A, Bt);
  short8 af[4][2], bf[4][2];
  f32x4 acc[8][4];
  ACC_ZERO();
  GEMM256_MAINLOOP();

  const int rb = (lane >> 4) * 4;
  const int orow = m0 + (w >> 2) * 128;
  const int ocol = n0 + (w & 3) * 64;
#pragma unroll
  for (int i = 0; i < 8; ++i)
#pragma unroll
    for (int j = 0; j < 4; ++j) {
      const int col = ocol + j * 16 + fr;
      const float bj = bias[col];
#pragma unroll
      for (int r = 0; r < 4; ++r)
        Cout[(size_t)(orow + i * 16 + rb + r) * N + col] = acc[i][j][r] + bj;
    }
}

// ---------------- Q-GEMM + FUSED ATTENTION (m-DESCENDING: L3 timing) ----------------
// Reads hs_b tail-first (resident from prepc); writes q_buf m-low LAST so the
// m-ascending O-GEMM's first reads are L3 hits.
__global__ __launch_bounds__(512, 1) void k_gemm256qa(const u16* __restrict__ A,
                                                      const u16* __restrict__ Bt,
                                                      const u16* __restrict__ Kbuf,
                                                      const u16* __restrict__ VTg,
                                                      u16* __restrict__ Obuf) {
  GEMM256_COMMON(1);
  GSRC_INIT(A, Bt);
  short8 af[4][2], bf[4][2];
  f32x4 acc[8][4];
  ACC_ZERO();
  GEMM256_MAINLOOP();

  const int bb = m0 >> 12;                    // batch (tiles never cross 4096-row bound)
  const int hd = (tile % 5) * 4 + (w & 3);    // head
  const int orow = m0 + (w >> 2) * 128;
  const int cb = fr, kq = lane >> 4, kgu = kq * 8;

  u16* ldsb = (u16*)lds;
  u16* Qc = ldsb + w * 2304;                  // [32][72]
  u16* Pw = ldsb + 8 * 2304 + w * 3328;       // [32][104]

  {
    short8 zz;
#pragma unroll
    for (int e = 0; e < 8; ++e) zz[e] = 0;
    *(short8*)(Pw + (lane >> 1) * 104 + 80 + (lane & 1) * 8) = zz;
  }

  short8 kf[5][2];
#pragma unroll
  for (int j = 0; j < 5; ++j)
#pragma unroll
    for (int t2 = 0; t2 < 2; ++t2)
      kf[j][t2] = *(const short8*)(Kbuf + (size_t)(bb * 77 + j * 16 + cb) * 1280 +
                                   hd * 64 + t2 * 32 + kgu);
  short8 vf[4][3];
#pragma unroll
  for (int n = 0; n < 4; ++n)
#pragma unroll
    for (int t2 = 0; t2 < 3; ++t2)
      vf[n][t2] = *(const short8*)(VTg + (size_t)((bb * 20 + hd) * 64 + n * 16 + cb) * 96 +
                                   t2 * 32 + kgu);

#pragma unroll
  for (int c = 0; c < 4; ++c) {
#pragma unroll
    for (int i2 = 0; i2 < 2; ++i2)
#pragma unroll
      for (int j = 0; j < 4; ++j)
#pragma unroll
        for (int r = 0; r < 4; ++r)
          Qc[(i2 * 16 + kq * 4 + r) * 72 + j * 16 + fr] =
              f2bf(acc[2 * c + i2][j][r] * QSCALE);
    short8 qf[2][2];
#pragma unroll
    for (int i2 = 0; i2 < 2; ++i2)
#pragma unroll
      for (int t2 = 0; t2 < 2; ++t2)
        qf[i2][t2] = *(const short8*)(Qc + (i2 * 16 + cb) * 72 + t2 * 32 + kgu);

    f32x4 sc[2][5];
    {
      f32x4 zf = {0.f, 0.f, 0.f, 0.f};
#pragma unroll
      for (int i2 = 0; i2 < 2; ++i2)
#pragma unroll
        for (int j = 0; j < 5; ++j) sc[i2][j] = zf;
    }
#pragma unroll
    for (int t2 = 0; t2 < 2; ++t2)
#pragma unroll
      for (int i2 = 0; i2 < 2; ++i2)
#pragma unroll
        for (int j = 0; j < 5; ++j)
          sc[i2][j] = __builtin_amdgcn_mfma_f32_16x16x32_bf16(
              qf[i2][t2], kf[j][t2], sc[i2][j], 0, 0, 0);

    float inv[2][4];
#pragma unroll
    for (int i2 = 0; i2 < 2; ++i2) {
#pragma unroll
      for (int r = 0; r < 4; ++r) {
        float sum = 0.f;
#pragma unroll
        for (int j = 0; j < 4; ++j) {
          float pv = exp2f(sc[i2][j][r]);
          sc[i2][j][r] = pv;
          sum += pv;
        }
        {
          float pv = (cb < 13) ? exp2f(sc[i2][4][r]) : 0.f;
          sc[i2][4][r] = pv;
          sum += pv;
        }
#pragma unroll
        for (int mk = 8; mk >= 1; mk >>= 1) sum += __shfl_xor(sum, mk, 64);
        inv[i2][r] = 1.f / sum;
      }
    }

#pragma unroll
    for (int i2 = 0; i2 < 2; ++i2)
#pragma unroll
      for (int j = 0; j < 5; ++j)
#pragma unroll
        for (int r = 0; r < 4; ++r)
          Pw[(i2 * 16 + kq * 4 + r) * 104 + j * 16 + cb] = f2bf(sc[i2][j][r]);

    f32x4 o[2][4];
    {
      f32x4 zf = {0.f, 0.f, 0.f, 0.f};
#pragma unroll
      for (int i2 = 0; i2 < 2; ++i2)
#pragma unroll
        for (int n = 0; n < 4; ++n) o[i2][n] = zf;
    }
#pragma unroll
    for (int t2 = 0; t2 < 3; ++t2) {
      short8 pf[2];
#pragma unroll
      for (int i2 = 0; i2 < 2; ++i2)
        pf[i2] = *(const short8*)(Pw + (i2 * 16 + cb) * 104 + t2 * 32 + kgu);
#pragma unroll
      for (int i2 = 0; i2 < 2; ++i2)
#pragma unroll
        for (int n = 0; n < 4; ++n)
          o[i2][n] = __builtin_amdgcn_mfma_f32_16x16x32_bf16(
              pf[i2], vf[n][t2], o[i2][n], 0, 0, 0);
    }

#pragma unroll
    for (int i2 = 0; i2 < 2; ++i2)
#pragma unroll
      for (int n = 0; n < 4; ++n)
#pragma unroll
        for (int r = 0; r < 4; ++r)
          Qc[(i2 * 16 + kq * 4 + r) * 72 + n * 16 + cb] =
              f2bf(o[i2][n][r] * inv[i2][r]);
    {
      const int lr2 = lane >> 3, lc2 = (lane & 7) * 8;
#pragma unroll
      for (int it = 0; it < 4; ++it) {
        const int rl = it * 8 + lr2;
        short8 v = *(const short8*)(Qc + rl * 72 + lc2);
        *(short8*)(Obuf + (size_t)(orow + c * 32 + rl) * 1280 + hd * 64 + lc2) = v;
      }
    }
  }
}

// ---------------- launch ----------------
extern "C" void kernel_launch(void* const* d_in, const int* in_sizes, int n_in,
                              void* d_out, int out_size, void* d_ws, size_t ws_size,
                              hipStream_t stream) {
  (void)in_sizes; (void)n_in; (void)out_size; (void)ws_size;
  const float* hs  = (const float*)d_in[0];
  const float* ehs = (const float*)d_in[1];
  const float* Wq  = (const float*)d_in[2];
  const float* Wk  = (const float*)d_in[3];
  const float* Wv  = (const float*)d_in[4];
  const float* Wo  = (const float*)d_in[5];
  const float* bo  = (const float*)d_in[6];
  const float* qd  = (const float*)d_in[7];
  const float* qu  = (const float*)d_in[8];
  const float* kd  = (const float*)d_in[9];
  const float* ku  = (const float*)d_in[10];
  const float* vd  = (const float*)d_in[11];
  const float* vu  = (const float*)d_in[12];
  const float* od  = (const float*)d_in[13];
  const float* ou  = (const float*)d_in[14];

  char* p = (char*)d_ws;
  u16* q_buf = (u16*)p;  p += (size_t)65536 * 1280 * 2;  // attn output (bf16)
  u16* wq_t  = (u16*)p;  p += (size_t)1280 * 1280 * 2;
  u16* wo_t  = (u16*)p;  p += (size_t)1280 * 1280 * 2;
  u16* wk_t  = (u16*)p;  p += (size_t)1280 * 768 * 2;
  u16* wv_t  = (u16*)p;  p += (size_t)1280 * 768 * 2;
  u16* ehs_b = (u16*)p;  p += (size_t)1280 * 768 * 2;
  u16* k_buf = (u16*)p;  p += (size_t)1280 * 1280 * 2;
  u16* vt    = (u16*)p;  p += (size_t)16 * 20 * 64 * 96 * 2;  // V^T [b][h][d][96]
  u16* hs_b  = (u16*)d_out;   // bf16 scratch in d_out; overwritten by final GEMM

  k_prepc<<<47520, 256, 0, stream>>>(hs, hs_b, ehs, ehs_b, vt,
                                     Wq, qd, qu, wq_t,
                                     Wk, kd, ku, wk_t,
                                     Wv, vd, vu, wv_t,
                                     Wo, od, ou, wo_t);

  k_gemmKV<<<dim3(10, 10, 2), 256, 0, stream>>>(ehs_b, wk_t, wv_t, k_buf, vt);

  k_gemm256qa<<<1280, 512, 0, stream>>>(hs_b, wq_t, k_buf, vt, q_buf);   // m-desc

  k_gemm256f<<<1280, 512, 0, stream>>>(q_buf, wo_t, (float*)d_out, bo);  // m-asc
}